// Round 9
// baseline (78.085 us; speedup 1.0000x reference)
//
#include <hip/hip_runtime.h>
#include <stdint.h>

#define IN_F   8192
#define OUT_F  8192
#define M_TOK  32
#define BN     32      // output channels per block (grid 256 = 1 block/CU)
#define BK     256     // K elements staged per iteration (1KB/stream DRAM burst)
#define NIT    (IN_F / BK)   // 32
#define PF     2       // prefetch depth: issue->consume ~1 full iter (~2900cy) >> HBM latency
#define LDSS   264     // BK + 8 pad (528B stride -> free 2-way bank alias class)

typedef float  f32x4  __attribute__((ext_vector_type(4)));
typedef short  short8 __attribute__((ext_vector_type(8)));

// Barrier without vmcnt drain: LDS writes ordered, global prefetch stays in flight.
#define LDS_BARRIER() do {                                   \
    asm volatile("s_waitcnt lgkmcnt(0)" ::: "memory");       \
    __builtin_amdgcn_s_barrier();                            \
} while (0)

// pack two fp32 into two bf16 (truncation; exact for int8-valued floats;
// measured absmax 4.0 vs threshold 13.12 across rounds 2/4/5/6/7/8)
__device__ inline unsigned pk_bf16(float f0, float f1) {
    unsigned u0 = __builtin_bit_cast(unsigned, f0);
    unsigned u1 = __builtin_bit_cast(unsigned, f1);
    return (u0 >> 16) | (u1 & 0xFFFF0000u);
}

// R2 structure (52.8us proven), ONE lever vs R2: BK 128->256 with PF=2 kept.
// (R7's BK=256 regression was the PF=1 confound -- prefetch window < latency.)
// Tests the DRAM-granularity theory: 512B/stream slices -> 4 visits per 2KB
// page at ~1460cy spacing explain the measured 4.9 TB/s effective read BW.
__global__ __launch_bounds__(256, 1) void qlin_mfma(
    const float* __restrict__ x, const int* __restrict__ wq,
    const float* __restrict__ scale, float* __restrict__ out) {

    __shared__ ushort ldsA[2][M_TOK][LDSS];  // x tile bf16 (33 KB x 2)
    __shared__ ushort ldsW[2][BN][LDSS];     // W tile bf16 (33 KB x 2) -> 132 KB total

    const int t  = threadIdx.x;
    const int o0 = blockIdx.x * BN;

    // staging: 256 threads -> 32 rows x 8 chunks of 32 elements (128B/thread, coalesced)
    const int r  = t >> 3;          // row 0..31
    const int cc = (t & 7) * 32;    // element col base 0..224

    const float* xp = x  + (size_t)r * IN_F + cc;
    const int*   wp = wq + (size_t)(o0 + r) * IN_F + cc;   // int8-valued, stored int32

    float4 abuf[PF][8];   // 32 fp32 / thread / iter
    int4   wbuf[PF][8];   // 32 int32 / thread / iter

    #pragma unroll
    for (int p = 0; p < PF; ++p) {
        #pragma unroll
        for (int q = 0; q < 8; ++q) {
            abuf[p][q] = *reinterpret_cast<const float4*>(xp + p * BK + 4 * q);
            wbuf[p][q] = *reinterpret_cast<const int4*>(wp + p * BK + 4 * q);
        }
    }

    // compute decomposition: 4 waves, one 16x16 output tile each
    const int wid  = t >> 6;
    const int lane = t & 63;
    const int mt   = wid & 1;          // token half
    const int nt   = wid >> 1;         // channel half
    const int frow = lane & 15;
    const int fk   = (lane >> 4) * 8;

    f32x4 acc = {0.f, 0.f, 0.f, 0.f};

    for (int base = 0; base < NIT; base += PF) {
        #pragma unroll
        for (int p = 0; p < PF; ++p) {
            const int it  = base + p;
            const int buf = it & 1;

            // ---- stage x (fp32 -> bf16): 32 elems -> 4x uint4 ----
            #pragma unroll
            for (int h = 0; h < 4; ++h) {
                float4 v0 = abuf[p][2 * h], v1 = abuf[p][2 * h + 1];
                uint4 w0;
                w0.x = pk_bf16(v0.x, v0.y); w0.y = pk_bf16(v0.z, v0.w);
                w0.z = pk_bf16(v1.x, v1.y); w0.w = pk_bf16(v1.z, v1.w);
                *reinterpret_cast<uint4*>(&ldsA[buf][r][cc + 8 * h]) = w0;
            }
            // ---- stage W (int32 -> bf16; exact, |v| <= 128) ----
            #pragma unroll
            for (int h = 0; h < 4; ++h) {
                int4 a0 = wbuf[p][2 * h], a1 = wbuf[p][2 * h + 1];
                uint4 w0;
                w0.x = pk_bf16((float)a0.x, (float)a0.y);
                w0.y = pk_bf16((float)a0.z, (float)a0.w);
                w0.z = pk_bf16((float)a1.x, (float)a1.y);
                w0.w = pk_bf16((float)a1.z, (float)a1.w);
                *reinterpret_cast<uint4*>(&ldsW[buf][r][cc + 8 * h]) = w0;
            }

            // ---- issue loads PF iterations ahead (survive lgkm-only barrier) ----
            const int nit = it + PF;
            if (nit < NIT) {
                const size_t off = (size_t)nit * BK;
                #pragma unroll
                for (int q = 0; q < 8; ++q) {
                    abuf[p][q] = *reinterpret_cast<const float4*>(xp + off + 4 * q);
                    wbuf[p][q] = *reinterpret_cast<const int4*>(wp + off + 4 * q);
                }
            }

            LDS_BARRIER();   // lgkm-only: prefetch not drained

            // ---- compute: 8 K-substeps of 32 ----
            const ushort* aB = &ldsA[buf][mt * 16 + frow][fk];
            const ushort* wB = &ldsW[buf][nt * 16 + frow][fk];
            #pragma unroll
            for (int ks = 0; ks < 8; ++ks) {
                short8 af = *reinterpret_cast<const short8*>(aB + ks * 32);
                short8 bf = *reinterpret_cast<const short8*>(wB + ks * 32);
                acc = __builtin_amdgcn_mfma_f32_16x16x32_bf16(af, bf, acc, 0, 0, 0);
            }
            // single barrier/iter: same-buffer WAR separated by the next barrier
        }
    }

    // ---- epilogue: per-channel scale, store ----
    // C/D layout (m89-verified): col = lane&15, row = (lane>>4)*4 + reg
    const int ocol = o0 + nt * 16 + frow;
    const float s  = scale[ocol];
    const int  m0  = mt * 16 + (lane >> 4) * 4;
    #pragma unroll
    for (int rg = 0; rg < 4; ++rg)
        out[(size_t)(m0 + rg) * OUT_F + ocol] = acc[rg] * s;
}

extern "C" void kernel_launch(void* const* d_in, const int* in_sizes, int n_in,
                              void* d_out, int out_size, void* d_ws, size_t ws_size,
                              hipStream_t stream) {
    const float* x  = (const float*)d_in[0];
    const int*   wq = (const int*)d_in[1];   // int8-valued weights stored as int32
    const float* sc = (const float*)d_in[2];
    float* out = (float*)d_out;

    qlin_mfma<<<OUT_F / BN, 256, 0, stream>>>(x, wq, sc, out);
}

// Round 10
// 64.899 us; speedup vs baseline: 1.2032x; 1.2032x over previous
//
#include <hip/hip_runtime.h>
#include <stdint.h>

#define IN_F   8192
#define OUT_F  8192
#define M_TOK  32
#define BN     32            // output channels per block (grid 256 = 1 block/CU)
#define BK     128           // K elements per tile
#define NIT    (IN_F / BK)   // 64
#define NBUF   4             // LDS tile depth (STAGE issued 2 iters ahead)

typedef float  f32x4  __attribute__((ext_vector_type(4)));
typedef short  short8 __attribute__((ext_vector_type(8)));

// pack two fp32 into two bf16 (truncation; exact for int8-valued floats;
// measured absmax 4.0 vs threshold 13.12 across rounds 2..9)
__device__ inline unsigned pk_bf16(float f0, float f1) {
    unsigned u0 = __builtin_bit_cast(unsigned, f0);
    unsigned u1 = __builtin_bit_cast(unsigned, f1);
    return (u0 >> 16) | (u1 & 0xFFFF0000u);
}

// async global->LDS DMA, 16B per lane; LDS dest = wave-uniform base + lane*16
__device__ inline void gload16(const void* gp, void* lp) {
    __builtin_amdgcn_global_load_lds(
        (const __attribute__((address_space(1))) unsigned int*)gp,
        (__attribute__((address_space(3))) unsigned int*)lp,
        16, 0, 0);
}

// ---- pre-pass: x fp32 -> bf16 (512 KB scratch; enables DMA-staging x) ----
__global__ __launch_bounds__(256) void xconv(
    const float* __restrict__ x, ushort* __restrict__ xb) {
    const size_t jj = (size_t)blockIdx.x * 256 + threadIdx.x;  // 16 elems/thread
    const float* p = x + jj * 16;
    float4 v0 = *reinterpret_cast<const float4*>(p);
    float4 v1 = *reinterpret_cast<const float4*>(p + 4);
    float4 v2 = *reinterpret_cast<const float4*>(p + 8);
    float4 v3 = *reinterpret_cast<const float4*>(p + 12);
    uint4 w0, w1;
    w0.x = pk_bf16(v0.x, v0.y); w0.y = pk_bf16(v0.z, v0.w);
    w0.z = pk_bf16(v1.x, v1.y); w0.w = pk_bf16(v1.z, v1.w);
    w1.x = pk_bf16(v2.x, v2.y); w1.y = pk_bf16(v2.z, v2.w);
    w1.z = pk_bf16(v3.x, v3.y); w1.w = pk_bf16(v3.z, v3.w);
    *reinterpret_cast<uint4*>(xb + jj * 16)     = w0;
    *reinterpret_cast<uint4*>(xb + jj * 16 + 8) = w1;
}

// ---- main: DMA-staged (global_load_lds), counted vmcnt (never 0 in loop),
// 4-deep LDS tiles, convert-after-ds_read. Staging has ZERO VALU and zero
// VGPR traffic; per-CU DMA queue always holds 1-2 tiles -> HBM never idles.
// LDS linear rows (DMA requirement) are bank-degenerate; fixed by both-sides
// XOR chunk swizzle: source chunk = p ^ row at stage, addr chunk = g ^ row at read.
__global__ __launch_bounds__(256, 1) void qlin_dma(
    const ushort* __restrict__ xb, const int* __restrict__ wq,
    const float* __restrict__ scale, float* __restrict__ out) {

    __shared__ int    ldsW[NBUF][32 * 128];   // raw int32 W tiles (16 KB each)
    __shared__ ushort ldsX[NBUF][32 * 128];   // bf16 x tiles (8 KB each) -> 96 KB total

    const int t    = threadIdx.x;
    const int wid  = t >> 6;
    const int lane = t & 63;
    const int o0   = blockIdx.x * BN;

    const int wrow = 8 * wid;        // this wave stages rows wrow..wrow+7

    // compute decomposition: 4 waves, one 16x16 tile each (R2-verified mapping)
    const int mt   = wid & 1;
    const int nt   = wid >> 1;
    const int frow = lane & 15;
    const int j    = lane >> 4;
    const int rowW = nt * 16 + frow;
    const int rowX = mt * 16 + frow;

    f32x4 acc = {0.f, 0.f, 0.f, 0.f};

    // stage tile tt into buffer buf: W 4 instrs/wave (1KB each), x 2 instrs/wave
    auto STAGE = [&](int tt, int buf) {
        #pragma unroll
        for (int q = 0; q < 4; ++q) {
            const int row = wrow + 2 * q + (lane >> 5);
            const int src = (lane & 31) ^ row;                   // 16B-chunk swizzle
            const int* gp = wq + (size_t)(o0 + row) * IN_F + tt * BK + src * 4;
            gload16(gp, &ldsW[buf][(wrow + 2 * q) * 128]);
        }
        #pragma unroll
        for (int q = 0; q < 2; ++q) {
            const int row = wrow + 4 * q + (lane >> 4);
            const int src = (lane & 15) ^ (row & 15);            // 16B-chunk swizzle
            const ushort* gp = xb + (size_t)row * IN_F + tt * BK + src * 8;
            gload16(gp, &ldsX[buf][(wrow + 4 * q) * 128]);
        }
    };

    STAGE(0, 0);
    STAGE(1, 1);

    for (int tt = 0; tt < NIT; ++tt) {
        const int buf = tt & 3;

        if (tt + 2 < NIT) {
            STAGE(tt + 2, (tt + 2) & 3);
            // wait for tile tt only: 12 newer (tiles tt+1, tt+2) stay in flight
            asm volatile("s_waitcnt vmcnt(12)" ::: "memory");
        } else if (tt + 1 < NIT) {
            asm volatile("s_waitcnt vmcnt(6)" ::: "memory");
        } else {
            asm volatile("s_waitcnt vmcnt(0)" ::: "memory");
        }
        __builtin_amdgcn_s_barrier();   // all waves' tile tt landed; also orders
                                        // prior-iter LDS reads vs next DMA (WAR:
                                        // write of buf b at iter tt is >=1 full
                                        // barrier after its last read at tt-2)

        const int*    Wb = ldsW[buf];
        const ushort* Xb = ldsX[buf];
        #pragma unroll
        for (int ks = 0; ks < 4; ++ks) {
            const int g = ks * 8 + j * 2;   // 16B-chunk of frag k-base in W row
            int4 w0 = *reinterpret_cast<const int4*>(&Wb[rowW * 128 + (((g    ) ^ rowW) << 2)]);
            int4 w1 = *reinterpret_cast<const int4*>(&Wb[rowW * 128 + (((g + 1) ^ rowW) << 2)]);
            uint4 u;
            u.x = pk_bf16((float)w0.x, (float)w0.y);
            u.y = pk_bf16((float)w0.z, (float)w0.w);
            u.z = pk_bf16((float)w1.x, (float)w1.y);
            u.w = pk_bf16((float)w1.z, (float)w1.w);
            short8 bw = __builtin_bit_cast(short8, u);
            const int cx = (ks * 4 + j) ^ frow;   // 16B-chunk of frag in x row
            short8 af = *reinterpret_cast<const short8*>(&Xb[rowX * 128 + cx * 8]);
            acc = __builtin_amdgcn_mfma_f32_16x16x32_bf16(af, bw, acc, 0, 0, 0);
        }
    }

    // ---- epilogue: per-channel scale, store ----
    // C/D layout (m89-verified): col = lane&15, row = (lane>>4)*4 + reg
    const int   ocol = o0 + nt * 16 + frow;
    const float s    = scale[ocol];
    const int   m0   = mt * 16 + (lane >> 4) * 4;
    #pragma unroll
    for (int rg = 0; rg < 4; ++rg)
        out[(size_t)(m0 + rg) * OUT_F + ocol] = acc[rg] * s;
}

extern "C" void kernel_launch(void* const* d_in, const int* in_sizes, int n_in,
                              void* d_out, int out_size, void* d_ws, size_t ws_size,
                              hipStream_t stream) {
    const float* x  = (const float*)d_in[0];
    const int*   wq = (const int*)d_in[1];   // int8-valued weights stored as int32
    const float* sc = (const float*)d_in[2];
    float* out = (float*)d_out;
    ushort* xb = (ushort*)d_ws;              // 32*8192 bf16 = 512 KB scratch

    xconv<<<(M_TOK * IN_F) / (256 * 16), 256, 0, stream>>>(x, xb);
    qlin_dma<<<OUT_F / BN, 256, 0, stream>>>(xb, wq, sc, out);
}